// Round 7
// baseline (346.391 us; speedup 1.0000x reference)
//
#include <hip/hip_runtime.h>
#include <math.h>

#define B_    64
#define W_    128
#define N_    40
#define FIN   66
#define HID   100
#define NEWD  71
#define MSEQ  10
#define NBLK  256
#define NTHR  768   // 12 waves: 9 compute + 3 staging
#define E_    240

#define NGU   150   // gate units: 25 tiles * 6 kc
#define NU    250   // + decay-mini units: 25 tiles * 4 kc (rows duplicated x4)

// hx row: 2 parity regions of 192 cols ([0..99]=h [100..170]=xe [171]=1 [172..191]=0)
#define HROW  392
#define CROW  264   // cx row: 2 parity regions of 128 ([0..99]=c [100]=1 [101..127]=0)
#define ROWH(m) ((m)*HROW + (((m)>>3)<<3))
#define ROWC(m) ((m)*CROW + (((m)>>3)<<3))
#define HXSZ  (15*HROW + 8 + HROW)   // 6280
#define CXSZ  (15*CROW + 8 + CROW)   // 4232

typedef float    f32x4 __attribute__((ext_vector_type(4)));
typedef _Float16 f16x4 __attribute__((ext_vector_type(4)));
typedef _Float16 f16x8 __attribute__((ext_vector_type(8)));

__device__ __forceinline__ float sig_(float x) {
    return __builtin_amdgcn_rcpf(1.0f + __expf(-x));
}
__device__ __forceinline__ float tanh_(float x) {
    return fmaf(2.0f, __builtin_amdgcn_rcpf(1.0f + __expf(-2.0f * x)), -1.0f);
}

// lgkm-only barrier: LDS visibility without draining global prefetch (vmcnt)
#define LBAR() do {                                            \
    asm volatile("s_waitcnt lgkmcnt(0)" ::: "memory");         \
    __builtin_amdgcn_s_barrier();                              \
    asm volatile("" ::: "memory");                             \
} while (0)

// ---------------------------------------------------------------------------
// Repack weights into f16 A-fragments for mfma_f32_16x16x32_f16 (r6 layout).
// GATE (u<150): rows interleaved R=4*unit+gate -> src row gate*100+unit.
//   k<100: Wall; 100..170: Uall; k==171: Wall_b+Uall_b (bias-as-input); else 0.
// DECAY-MINI (u>=150): row R -> Wd row 4T+(R>>2) (4x duplicated rows).
//   k<100: Wd; k==100: Wd_b; else 0.
// ---------------------------------------------------------------------------
__global__ void repack_kernel(const float* __restrict__ Wall_w,
                              const float* __restrict__ Uall_w,
                              const float* __restrict__ Wd_w,
                              const float* __restrict__ Wall_b,
                              const float* __restrict__ Uall_b,
                              const float* __restrict__ Wd_b,
                              _Float16* __restrict__ Wfrag)
{
    int idx = blockIdx.x * 256 + threadIdx.x;
    if (idx >= NU * 64) return;
    int u = idx >> 6, l = idx & 63;
    f16x8 v;
    #pragma unroll
    for (int e = 0; e < 8; ++e) {
        float wv = 0.0f;
        int k = ((l >> 4) << 3) + e;
        if (u < NGU) {
            int T = u / 6, j = u % 6;
            int R = T * 16 + (l & 15);
            int src = (R & 3) * 100 + (R >> 2);
            k += j * 32;
            if (k < 100)       wv = Wall_w[src * HID + k];
            else if (k < 171)  wv = Uall_w[src * NEWD + (k - 100)];
            else if (k == 171) wv = Wall_b[src] + Uall_b[src];
        } else {
            int du = u - NGU;
            int T = du >> 2, j = du & 3;
            int srcrow = 4 * T + ((l & 15) >> 2);
            k += j * 32;
            if (k < 100)       wv = Wd_w[srcrow * HID + k];
            else if (k == 100) wv = Wd_b[srcrow];
        }
        v[e] = (_Float16)wv;
    }
    *(f16x8*)(Wfrag + (size_t)idx * 8) = v;
}

// ---------------------------------------------------------------------------
// LSTM: 256 blocks x 768 threads (12 waves, 3/SIMD). ONE lgkm barrier per step.
// Waves 0..8 compute, NS=2 slots for wv {0,4} else 3; contiguous tiles
// base(wv) = 3wv - [wv>=1] - [wv>=5]  (exact 25-tile cover, no duplicates).
// Per step per wave: 6 bh + 4 bc b128 reads (shared across slots),
// 6*NS gate MFMA + 4*NS decay-mini MFMA, sig/tanh + c/h update in-register,
// write h/c f16 to parity p^1.
// Waves 9..11 staging: write xe(w+1)/ts(w+1) from regs preloaded a step ahead.
// ---------------------------------------------------------------------------
__global__ __launch_bounds__(NTHR, 3)
void lstm_kernel(const float* __restrict__ X, const float* __restrict__ ts,
                 const float* __restrict__ emb_pos, const float* __restrict__ emb_team,
                 const _Float16* __restrict__ Wfrag,
                 const float* __restrict__ lin_w, const float* __restrict__ lin_b,
                 float* __restrict__ nodes)
{
    __shared__ __align__(16) _Float16 hx[HXSZ];
    __shared__ __align__(16) _Float16 cx[CXSZ];
    __shared__ float ts_s[2][16];

    const int t = threadIdx.x, l = t & 63, wv = t >> 6;
    const int uoff = l >> 4, m = l & 15;
    const int r0 = blockIdx.x * MSEQ;
    const bool comp = (wv < 9);

    // ---- zero LDS ----
    for (int i = t; i < HXSZ; i += NTHR) hx[i] = (_Float16)0.0f;
    for (int i = t; i < CXSZ; i += NTHR) cx[i] = (_Float16)0.0f;
    if (t < 32) ((float*)ts_s)[t] = 0.0f;

    // ---- compute-wave slot config ----
    const int NS   = (wv == 0 || wv == 4) ? 2 : 3;
    const int base = 3 * wv - (wv >= 1 ? 1 : 0) - (wv >= 5 ? 1 : 0);
    const int Ts0 = base, Ts1 = base + 1, Ts2 = base + 2;
    const int Us0 = 4 * Ts0 + uoff, Us1 = 4 * Ts1 + uoff, Us2 = 4 * Ts2 + uoff;

    f16x8 af[3][6], ad[3][4];
    if (comp) {
        #pragma unroll
        for (int j = 0; j < 6; ++j) {
            af[0][j] = *(const f16x8*)(Wfrag + ((size_t)(Ts0 * 6 + j) * 64 + l) * 8);
            af[1][j] = *(const f16x8*)(Wfrag + ((size_t)(Ts1 * 6 + j) * 64 + l) * 8);
        }
        #pragma unroll
        for (int j = 0; j < 4; ++j) {
            ad[0][j] = *(const f16x8*)(Wfrag + ((size_t)(NGU + Ts0 * 4 + j) * 64 + l) * 8);
            ad[1][j] = *(const f16x8*)(Wfrag + ((size_t)(NGU + Ts1 * 4 + j) * 64 + l) * 8);
        }
        if (NS > 2) {
            #pragma unroll
            for (int j = 0; j < 6; ++j)
                af[2][j] = *(const f16x8*)(Wfrag + ((size_t)(Ts2 * 6 + j) * 64 + l) * 8);
            #pragma unroll
            for (int j = 0; j < 4; ++j)
                ad[2][j] = *(const f16x8*)(Wfrag + ((size_t)(NGU + Ts2 * 4 + j) * 64 + l) * 8);
        }
    }
    float creg0 = 0.f, creg1 = 0.f, creg2 = 0.f;

    // ---- staging roles (waves 9..11, t >= 576) ----
    const float* xld = nullptr; int xm = 0, xp = 0;
    const float* xcat = nullptr; int me = 0;
    const float* tsp = nullptr; int mt = 0;
    {
        int s = t - 576;
        if (s >= 0 && s < 160) {
            xm = s >> 4; xp = s & 15;
            int r = r0 + xm, b = r / N_, n = r % N_;
            xld = X + ((size_t)b * W_ * N_ + n) * FIN + 4 * xp;
        } else if (s >= 160 && s < 170) {
            me = s - 160;
            int r = r0 + me, b = r / N_, n = r % N_;
            xcat = X + ((size_t)b * W_ * N_ + n) * FIN;
        } else if (s >= 170 && s < 180) {
            mt = s - 170;
            int r = r0 + mt, b = r / N_, n = r % N_;
            tsp = ts + (size_t)b * W_ * N_ + n;
        }
    }
    __syncthreads();

    // ---- constant-1 bias inputs (both parities) ----
    if (t < 32) {
        int r = t & 15, pp = t >> 4;
        hx[ROWH(r) + pp * 192 + 171] = (_Float16)1.0f;
        cx[ROWC(r) + pp * 128 + 100] = (_Float16)1.0f;
    }
    // ---- stage xe(0)/ts(0) into parity 0 ----
    if (xld) {
        float2 a = *(const float2*)xld;
        float2 b2 = *(const float2*)(xld + 2);
        f16x4 v = {(_Float16)a.x, (_Float16)a.y, (_Float16)b2.x, (_Float16)b2.y};
        *(f16x4*)&hx[ROWH(xm) + 100 + 4 * xp] = v;
    }
    if (xcat) {
        float c0f = xcat[64], c1f = xcat[65];
        int ip = (int)c0f, itm = (int)c1f;
        int sp = ip > 0 ? ip - 1 : 0;   float fp  = ip > 0 ? 1.f : 0.f;
        int st = itm > 0 ? itm - 1 : 0; float ft_ = itm > 0 ? 1.f : 0.f;
        #pragma unroll
        for (int q = 0; q < 4; ++q) hx[ROWH(me) + 164 + q] = (_Float16)(emb_pos[sp * 4 + q] * fp);
        #pragma unroll
        for (int q = 0; q < 3; ++q) hx[ROWH(me) + 168 + q] = (_Float16)(emb_team[st * 3 + q] * ft_);
    }
    if (tsp) ts_s[0][mt] = tsp[0];

    // ---- preload regs for step 1 ----
    float2 pa = {0.f, 0.f}, pb = {0.f, 0.f};
    float pc0 = 0.f, pc1 = 0.f, ptv = 0.f;
    {
        const size_t off1 = (size_t)N_ * FIN;
        if (xld)  { pa = *(const float2*)(xld + off1); pb = *(const float2*)(xld + off1 + 2); }
        if (xcat) { pc0 = xcat[off1 + 64]; pc1 = xcat[off1 + 65]; }
        if (tsp)  ptv = tsp[(size_t)N_];
    }
    __syncthreads();

    const int rowhm = ROWH(m) + (uoff << 3);
    const int rowcm = ROWC(m) + (uoff << 3);
    const int rowhw = ROWH(m);
    const int rowcw = ROWC(m);

    // ---- main loop: ONE barrier per step ----
    for (int w = 0; w < W_; ++w) {
        const int p = w & 1, np = p ^ 1;
        if (comp) {
            f32x4 aG0 = {0.f,0.f,0.f,0.f}, aG1 = {0.f,0.f,0.f,0.f}, aG2 = {0.f,0.f,0.f,0.f};
            f32x4 aD0 = {0.f,0.f,0.f,0.f}, aD1 = {0.f,0.f,0.f,0.f}, aD2 = {0.f,0.f,0.f,0.f};
            const int hb = rowhm + p * 192;
            #pragma unroll
            for (int j = 0; j < 6; ++j) {
                f16x8 bb = *(const f16x8*)&hx[hb + j * 32];
                aG0 = __builtin_amdgcn_mfma_f32_16x16x32_f16(af[0][j], bb, aG0, 0, 0, 0);
                aG1 = __builtin_amdgcn_mfma_f32_16x16x32_f16(af[1][j], bb, aG1, 0, 0, 0);
                if (NS > 2)
                    aG2 = __builtin_amdgcn_mfma_f32_16x16x32_f16(af[2][j], bb, aG2, 0, 0, 0);
            }
            const int cb = rowcm + p * 128;
            #pragma unroll
            for (int j = 0; j < 4; ++j) {
                f16x8 bc = *(const f16x8*)&cx[cb + j * 32];
                aD0 = __builtin_amdgcn_mfma_f32_16x16x32_f16(ad[0][j], bc, aD0, 0, 0, 0);
                aD1 = __builtin_amdgcn_mfma_f32_16x16x32_f16(ad[1][j], bc, aD1, 0, 0, 0);
                if (NS > 2)
                    aD2 = __builtin_amdgcn_mfma_f32_16x16x32_f16(ad[2][j], bc, aD2, 0, 0, 0);
            }
            if (m < MSEQ) {
                const float tsv = ts_s[p][m];
                const float e1 = tsv - 1.0f;
                {
                    float cs1 = tanh_(aD0[0]);
                    float cn = sig_(aG0[0]) * fmaf(cs1, e1, creg0) + sig_(aG0[1]) * sig_(aG0[3]);
                    creg0 = cn;
                    hx[rowhw + np * 192 + Us0] = (_Float16)(sig_(aG0[2]) * tanh_(cn));
                    cx[rowcw + np * 128 + Us0] = (_Float16)cn;
                }
                {
                    float cs1 = tanh_(aD1[0]);
                    float cn = sig_(aG1[0]) * fmaf(cs1, e1, creg1) + sig_(aG1[1]) * sig_(aG1[3]);
                    creg1 = cn;
                    hx[rowhw + np * 192 + Us1] = (_Float16)(sig_(aG1[2]) * tanh_(cn));
                    cx[rowcw + np * 128 + Us1] = (_Float16)cn;
                }
                if (NS > 2) {
                    float cs1 = tanh_(aD2[0]);
                    float cn = sig_(aG2[0]) * fmaf(cs1, e1, creg2) + sig_(aG2[1]) * sig_(aG2[3]);
                    creg2 = cn;
                    hx[rowhw + np * 192 + Us2] = (_Float16)(sig_(aG2[2]) * tanh_(cn));
                    cx[rowcw + np * 128 + Us2] = (_Float16)cn;
                }
            }
        } else {
            if (w + 1 < W_) {
                if (xld) {
                    f16x4 v = {(_Float16)pa.x, (_Float16)pa.y, (_Float16)pb.x, (_Float16)pb.y};
                    *(f16x4*)&hx[ROWH(xm) + np * 192 + 100 + 4 * xp] = v;
                }
                if (xcat) {
                    int ip = (int)pc0, itm = (int)pc1;
                    int sp = ip > 0 ? ip - 1 : 0;   float fp  = ip > 0 ? 1.f : 0.f;
                    int st = itm > 0 ? itm - 1 : 0; float ft_ = itm > 0 ? 1.f : 0.f;
                    #pragma unroll
                    for (int q = 0; q < 4; ++q) hx[ROWH(me) + np * 192 + 164 + q] = (_Float16)(emb_pos[sp * 4 + q] * fp);
                    #pragma unroll
                    for (int q = 0; q < 3; ++q) hx[ROWH(me) + np * 192 + 168 + q] = (_Float16)(emb_team[st * 3 + q] * ft_);
                }
                if (tsp) ts_s[np][mt] = ptv;
                if (w + 2 < W_) {
                    const size_t off = (size_t)(w + 2) * (N_ * FIN);
                    if (xld)  { pa = *(const float2*)(xld + off); pb = *(const float2*)(xld + off + 2); }
                    if (xcat) { pc0 = xcat[off + 64]; pc1 = xcat[off + 65]; }
                    if (tsp)  ptv = tsp[(size_t)(w + 2) * N_];
                }
            }
        }
        LBAR();
    }

    // ---- lin head: final h is in parity 0 ----
    for (int idx = t; idx < HID * MSEQ; idx += NTHR) {
        const int i = idx / MSEQ, mm = idx % MSEQ;
        const float* lr = lin_w + (size_t)i * HID;
        float acc2 = lin_b[i];
        for (int k = 0; k < HID; ++k)
            acc2 = fmaf(lr[k], (float)hx[ROWH(mm) + k], acc2);
        nodes[(size_t)(r0 + mm) * HID + i] = fmaxf(acc2, 0.0f);
    }
}

// ---------------------------------------------------------------------------
// Kernel B: per-batch GraphSAGE x2 + head. 512 threads, i-major mapping,
// float4 loads (weight-row reuse across 5/3 nodes per thread).
// ---------------------------------------------------------------------------
__global__ __launch_bounds__(512, 1)
void sage_kernel(const float* __restrict__ nodes, const int* __restrict__ edge,
                 const float* __restrict__ s1l, const float* __restrict__ s1lb,
                 const float* __restrict__ s1r,
                 const float* __restrict__ s2l, const float* __restrict__ s2lb,
                 const float* __restrict__ s2r,
                 const float* __restrict__ ow,  const float* __restrict__ ob,
                 float* __restrict__ out)
{
    __shared__ float nd[N_ * HID];
    __shared__ float agg[N_ * HID];
    __shared__ float g1[N_ * 64];
    __shared__ float agg2[N_ * 64];
    __shared__ float g2[N_ * 32];
    __shared__ float deg[N_];
    __shared__ float invdeg[N_];

    const int t = threadIdx.x;
    const int b = blockIdx.x;
    const int* esrc = edge;
    const int* edst = edge + E_;

    for (int i = t; i < N_ * HID; i += 512) {
        nd[i]  = nodes[(size_t)b * N_ * HID + i];
        agg[i] = 0.0f;
    }
    for (int i = t; i < N_; i += 512) deg[i] = 0.0f;
    __syncthreads();

    if (t < E_) atomicAdd(&deg[edst[t]], 1.0f);
    for (int i = t; i < E_ * HID; i += 512) {
        int e = i / HID, k = i % HID;
        atomicAdd(&agg[edst[e] * HID + k], nd[esrc[e] * HID + k]);
    }
    __syncthreads();
    for (int i = t; i < N_; i += 512) invdeg[i] = 1.0f / fmaxf(deg[i], 1.0f);
    __syncthreads();

    // sage1 -> g1 (40 x 64): i = t>>3 in [0,64), n = (t&7) + 8j, j<5
    {
        const int i = t >> 3, n0 = t & 7;
        const float4* lr = (const float4*)(s1l + (size_t)i * HID);
        const float4* rr = (const float4*)(s1r + (size_t)i * HID);
        float acc[5], id[5];
        #pragma unroll
        for (int j = 0; j < 5; ++j) {
            acc[j] = s1lb[i];
            id[j]  = invdeg[n0 + 8 * j];
        }
        for (int kq = 0; kq < 25; ++kq) {
            float4 lw = lr[kq], rw = rr[kq];
            #pragma unroll
            for (int j = 0; j < 5; ++j) {
                const int n = n0 + 8 * j;
                float4 ag = *(const float4*)&agg[n * HID + 4 * kq];
                float4 nv = *(const float4*)&nd[n * HID + 4 * kq];
                acc[j] = fmaf(lw.x, ag.x * id[j], acc[j]);
                acc[j] = fmaf(lw.y, ag.y * id[j], acc[j]);
                acc[j] = fmaf(lw.z, ag.z * id[j], acc[j]);
                acc[j] = fmaf(lw.w, ag.w * id[j], acc[j]);
                acc[j] = fmaf(rw.x, nv.x, acc[j]);
                acc[j] = fmaf(rw.y, nv.y, acc[j]);
                acc[j] = fmaf(rw.z, nv.z, acc[j]);
                acc[j] = fmaf(rw.w, nv.w, acc[j]);
            }
        }
        #pragma unroll
        for (int j = 0; j < 5; ++j)
            g1[(n0 + 8 * j) * 64 + i] = fmaxf(acc[j], 0.0f);
    }
    __syncthreads();
    for (int i = t; i < N_ * 64; i += 512) agg2[i] = 0.0f;
    __syncthreads();
    for (int i = t; i < E_ * 64; i += 512) {
        int e = i >> 6, k = i & 63;
        atomicAdd(&agg2[edst[e] * 64 + k], g1[esrc[e] * 64 + k]);
    }
    __syncthreads();

    // sage2 -> g2 (40 x 32): i = t>>4 in [0,32), n = (t&15) + 16j
    {
        const int i = t >> 4, n0 = t & 15;
        const float4* lr = (const float4*)(s2l + (size_t)i * 64);
        const float4* rr = (const float4*)(s2r + (size_t)i * 64);
        float acc[3] = {s2lb[i], s2lb[i], s2lb[i]};
        float id[3];
        #pragma unroll
        for (int j = 0; j < 3; ++j) {
            int n = n0 + 16 * j;
            id[j] = (n < N_) ? invdeg[n] : 0.0f;
        }
        for (int kq = 0; kq < 16; ++kq) {
            float4 lw = lr[kq], rw = rr[kq];
            #pragma unroll
            for (int j = 0; j < 3; ++j) {
                const int n = n0 + 16 * j;
                if (n < N_) {
                    float4 ag = *(const float4*)&agg2[n * 64 + 4 * kq];
                    float4 nv = *(const float4*)&g1[n * 64 + 4 * kq];
                    acc[j] = fmaf(lw.x, ag.x * id[j], acc[j]);
                    acc[j] = fmaf(lw.y, ag.y * id[j], acc[j]);
                    acc[j] = fmaf(lw.z, ag.z * id[j], acc[j]);
                    acc[j] = fmaf(lw.w, ag.w * id[j], acc[j]);
                    acc[j] = fmaf(rw.x, nv.x, acc[j]);
                    acc[j] = fmaf(rw.y, nv.y, acc[j]);
                    acc[j] = fmaf(rw.z, nv.z, acc[j]);
                    acc[j] = fmaf(rw.w, nv.w, acc[j]);
                }
            }
        }
        #pragma unroll
        for (int j = 0; j < 3; ++j) {
            int n = n0 + 16 * j;
            if (n < N_) g2[n * 32 + i] = fmaxf(acc[j], 0.0f);
        }
    }
    __syncthreads();

    // output head -> (40, 2)
    if (t < N_ * 2) {
        const int n = t >> 1, c = t & 1;
        const float4* wr = (const float4*)(ow + (size_t)c * 32);
        float acc = ob[c];
        for (int kq = 0; kq < 8; ++kq) {
            float4 w4 = wr[kq];
            float4 g4 = *(const float4*)&g2[n * 32 + 4 * kq];
            acc = fmaf(w4.x, g4.x, acc);
            acc = fmaf(w4.y, g4.y, acc);
            acc = fmaf(w4.z, g4.z, acc);
            acc = fmaf(w4.w, g4.w, acc);
        }
        out[((size_t)b * N_ + n) * 2 + c] = fmaxf(acc, 0.0f);
    }
}

extern "C" void kernel_launch(void* const* d_in, const int* in_sizes, int n_in,
                              void* d_out, int out_size, void* d_ws, size_t ws_size,
                              hipStream_t stream) {
    const float* X        = (const float*)d_in[0];
    const float* ts       = (const float*)d_in[1];
    const int*   edge     = (const int*)  d_in[2];
    const float* emb_pos  = (const float*)d_in[3];
    const float* emb_team = (const float*)d_in[4];
    const float* Wall_w   = (const float*)d_in[5];
    const float* Wall_b   = (const float*)d_in[6];
    const float* Uall_w   = (const float*)d_in[7];
    const float* Uall_b   = (const float*)d_in[8];
    const float* Wd_w     = (const float*)d_in[9];
    const float* Wd_b     = (const float*)d_in[10];
    const float* lin_w    = (const float*)d_in[11];
    const float* lin_b    = (const float*)d_in[12];
    const float* s1l      = (const float*)d_in[13];
    const float* s1lb     = (const float*)d_in[14];
    const float* s1r      = (const float*)d_in[15];
    const float* s2l      = (const float*)d_in[16];
    const float* s2lb     = (const float*)d_in[17];
    const float* s2r      = (const float*)d_in[18];
    const float* ow       = (const float*)d_in[19];
    const float* ob       = (const float*)d_in[20];

    float*     nodes = (float*)d_ws;                              // 1,024,000 B
    _Float16*  Wfrag = (_Float16*)((char*)d_ws + 1024000);        // 250*64*8*2 = 256,000 B

    repack_kernel<<<(NU * 64 + 255) / 256, 256, 0, stream>>>(Wall_w, Uall_w, Wd_w,
                                                             Wall_b, Uall_b, Wd_b, Wfrag);

    lstm_kernel<<<NBLK, NTHR, 0, stream>>>(X, ts, emb_pos, emb_team, Wfrag,
                                           lin_w, lin_b, nodes);
    sage_kernel<<<B_, 512, 0, stream>>>(nodes, edge, s1l, s1lb, s1r,
                                        s2l, s2lb, s2r, ow, ob, (float*)d_out);
}